// Round 15
// baseline (252.798 us; speedup 1.0000x reference)
//
#include <hip/hip_runtime.h>

#define TC_L    1024
#define TC_K    64
#define TC_LN   128
#define TC_NCLS 10
#define TC_DCAT 8320

typedef __attribute__((ext_vector_type(8))) short short8v;
typedef __attribute__((ext_vector_type(4))) short short4v;
typedef __attribute__((ext_vector_type(4))) float f32x4;

__device__ __forceinline__ unsigned short f2bf(float f) {
    unsigned int u = __float_as_uint(f);
    u = (u + 0x7FFFu + ((u >> 16) & 1u)) >> 16;
    return (unsigned short)u;
}

// ---------------------------------------------------------------------------
// K1: conv1  x[n,k,l] = sum_t w1[k,t] * X[n, l-4+t]   (pad 4)
__global__ __launch_bounds__(256) void k_conv1(
    const float* __restrict__ X, const float* __restrict__ w1, float* __restrict__ x)
{
    const int k = blockIdx.x, n = blockIdx.y;
    float w[9];
#pragma unroll
    for (int t = 0; t < 9; ++t) w[t] = w1[k * 9 + t];
    const float* xin = X + n * TC_L;
    float* out = x + (n * TC_K + k) * TC_L;
    for (int l = threadIdx.x; l < TC_L; l += 256) {
        float acc = 0.f;
#pragma unroll
        for (int t = 0; t < 9; ++t) {
            int idx = l - 4 + t;
            float v = (idx >= 0 && idx < TC_L) ? xin[idx] : 0.f;
            acc = fmaf(w[t], v, acc);
        }
        out[l] = acc;
    }
}

// ---------------------------------------------------------------------------
// K2pre (R12 layout): repack psi_m weights: w2r[og(32)][ic(64)][t(5)][q(2)],
// og = ocb*4+ocg (ocb 0..7), oc = og*2+q.
__global__ __launch_bounds__(256) void k_repack_w2(
    const float* __restrict__ w2, float* __restrict__ w2r)
{
    int i = blockIdx.x * 256 + threadIdx.x;   // 20480 total
    if (i < 20480) {
        int q = i & 1;
        int t = (i >> 1) % 5;
        int ic = (i / 10) & 63;
        int og = i / 640;
        w2r[i] = w2[(size_t)(og * 2 + q) * 320 + ic * 5 + t];
    }
}

// ---------------------------------------------------------------------------
// K2 (R14): psi_m conv, NO LDS, 2 oc/thread (R12 shape) + XCD swizzle (R13):
// flat grid 2048 (8 blk/CU); all 8 ocb-sharers of one (lc,n) slice on ONE XCD.
__global__ __launch_bounds__(256) void k_psim(
    const float* __restrict__ x, const float* __restrict__ w2r, float* __restrict__ xs)
{
    const int bid = blockIdx.x;                     // 0..2047
    const int swz = (bid & 7) * 256 + (bid >> 3);   // bijective (2048 % 8 == 0)
    const int ocb = swz & 7;                        // 0..7 -> oc base = ocb*8
    const int lcq = (swz >> 3) & 3;
    const int n   = swz >> 5;                       // 0..63
    const int lc  = lcq * 256;
    const int tid = threadIdx.x;
    const int lgrp = tid & 63;
    const int ocg  = __builtin_amdgcn_readfirstlane(tid >> 6);   // wave-uniform
    const int l0   = lgrp * 4;
    const bool lpad = (lc == 0) && (lgrp == 0);
    const bool rpad = (lc == 768) && (lgrp == 63);

    const float* __restrict__ wv = w2r + (size_t)(ocb * 4 + ocg) * 640; // uniform
    float acc[2][4] = {};
    const float* xn = x + (size_t)n * TC_K * TC_L;
#pragma unroll 4
    for (int ic = 0; ic < 64; ++ic) {
        const float* row = xn + ic * TC_L + lc;
        float4 va = *(const float4*)&row[l0];                    // l0..l0+3
        float2 vh = *(const float2*)&row[lpad ? l0 : (l0 - 2)];  // l0-2, l0-1
        float2 vb = *(const float2*)&row[l0 + 4];                // l0+4, l0+5
        if (lpad) { vh.x = 0.f; vh.y = 0.f; }
        if (rpad) { vb.x = 0.f; vb.y = 0.f; }
        float v[8] = {vh.x, vh.y, va.x, va.y, va.z, va.w, vb.x, vb.y};
        const float* wp = wv + ic * 10;                          // uniform
#pragma unroll
        for (int t = 0; t < 5; ++t) {
            float2 wa = *(const float2*)&wp[t * 2];              // -> s_load_dwordx2
            float w0 = wa.x, w1 = wa.y;
#pragma unroll
            for (int j = 0; j < 4; ++j) {
                acc[0][j] = fmaf(w0, v[j + t], acc[0][j]);
                acc[1][j] = fmaf(w1, v[j + t], acc[1][j]);
            }
        }
    }
#pragma unroll
    for (int q = 0; q < 2; ++q) {
        int oc = ocb * 8 + ocg * 2 + q;
        *(float4*)&xs[((size_t)n * TC_K + oc) * TC_L + lc + l0] =
            make_float4(acc[q][0], acc[q][1], acc[q][2], acc[q][3]);
    }
}

// ---------------------------------------------------------------------------
// K3: squash each row of 1024 in place
__global__ __launch_bounds__(256) void k_squash_rows(float* __restrict__ xs)
{
    const int row = blockIdx.x;
    float* p = xs + (size_t)row * TC_L;
    const int tid = threadIdx.x;
    float4 v = *(const float4*)&p[tid * 4];
    float part = v.x * v.x + v.y * v.y + v.z * v.z + v.w * v.w;
    __shared__ float red[256];
    red[tid] = part;
    __syncthreads();
    for (int s = 128; s > 0; s >>= 1) {
        if (tid < s) red[tid] += red[tid + s];
        __syncthreads();
    }
    float sq = red[0];
    float scale = sq / ((1.f + sq) * (sq + 1e-8f));
    v.x *= scale; v.y *= scale; v.z *= scale; v.w *= scale;
    *(float4*)&p[tid * 4] = v;
}

// ---------------------------------------------------------------------------
// K5a: Cell_B convs + bias + squash(last=128) -> xbS[n][j=8][s=8][128]
__global__ __launch_bounds__(256) void k_cellB_conv(
    const float* __restrict__ x, const float* __restrict__ wB, const float* __restrict__ bB,
    const float* __restrict__ wk, const float* __restrict__ bk, float* __restrict__ xbS)
{
    const int s = blockIdx.x;
    const int n = blockIdx.y;
    __shared__ float wBl[64 * 64];
    __shared__ float wkl[8 * 320];
    __shared__ float xb1[64][132];
    __shared__ float redq[8][33];
    const int tid = threadIdx.x;
    for (int i = tid; i < 4096; i += 256) wBl[i] = wB[i];
    for (int i = tid; i < 2560; i += 256) wkl[i] = wk[i];
    for (int i = tid; i < 64; i += 256) {
        xb1[i][0] = xb1[i][1] = xb1[i][130] = xb1[i][131] = 0.f;
    }
    __syncthreads();

    {
        const int t0  = (tid & 31) * 4;
        const int chg = tid >> 5;
        float acc[8][4] = {};
        const float* xbase = x + (size_t)n * TC_K * TC_L + s * TC_LN + t0;
        for (int k = 0; k < 64; ++k) {
            float4 xv = *(const float4*)&xbase[(size_t)k * TC_L];
            float v0 = xv.x, v1 = xv.y, v2 = xv.z, v3 = xv.w;
#pragma unroll
            for (int cc = 0; cc < 8; ++cc) {
                float w = wBl[(chg * 8 + cc) * 64 + k];
                acc[cc][0] = fmaf(w, v0, acc[cc][0]);
                acc[cc][1] = fmaf(w, v1, acc[cc][1]);
                acc[cc][2] = fmaf(w, v2, acc[cc][2]);
                acc[cc][3] = fmaf(w, v3, acc[cc][3]);
            }
        }
#pragma unroll
        for (int cc = 0; cc < 8; ++cc) {
            int ch = chg * 8 + cc;
            float b = bB[ch];
            xb1[ch][2 + t0 + 0] = acc[cc][0] + b;
            xb1[ch][2 + t0 + 1] = acc[cc][1] + b;
            xb1[ch][2 + t0 + 2] = acc[cc][2] + b;
            xb1[ch][2 + t0 + 3] = acc[cc][3] + b;
        }
    }
    __syncthreads();

    {
        const int t0 = (tid & 31) * 4;
        const int j  = tid >> 5;
        float acc[4] = {};
        for (int ch = 0; ch < 64; ++ch) {
            float4 va = *(const float4*)&xb1[ch][t0];
            float4 vb = *(const float4*)&xb1[ch][t0 + 4];
            float v[8] = {va.x, va.y, va.z, va.w, vb.x, vb.y, vb.z, vb.w};
            const float* wp = &wkl[j * 320 + ch * 5];
#pragma unroll
            for (int dw = 0; dw < 5; ++dw) {
                float w = wp[dw];
#pragma unroll
                for (int q = 0; q < 4; ++q) acc[q] = fmaf(w, v[q + dw], acc[q]);
            }
        }
        float b = bk[j];
#pragma unroll
        for (int q = 0; q < 4; ++q) acc[q] += b;
        float part = acc[0]*acc[0] + acc[1]*acc[1] + acc[2]*acc[2] + acc[3]*acc[3];
        redq[j][tid & 31] = part;
        __syncthreads();
        for (int st = 16; st > 0; st >>= 1) {
            if ((tid & 31) < st) redq[j][tid & 31] += redq[j][(tid & 31) + st];
            __syncthreads();
        }
        float sq = redq[j][0];
        float scale = sq / ((1.f + sq) * (sq + 1e-8f));
        float* outp = xbS + (((size_t)n * 8 + j) * 8 + s) * TC_LN + t0;
        *(float4*)outp = make_float4(acc[0]*scale, acc[1]*scale, acc[2]*scale, acc[3]*scale);
    }
}

// ---------------------------------------------------------------------------
// K5b: routing over s for Cell_B -> xB[n][j][t]
__global__ __launch_bounds__(128) void k_routeB(
    const float* __restrict__ xbS, float* __restrict__ xB)
{
    const int j = blockIdx.x, n = blockIdx.y;
    const int t = threadIdx.x;
    float xv[8];
    const float* base = xbS + ((size_t)n * 8 + j) * 8 * TC_LN;
#pragma unroll
    for (int s = 0; s < 8; ++s) xv[s] = base[s * TC_LN + t];

    __shared__ float red[128];
    __shared__ float redp[8][129];

    float sj = 0.f;
#pragma unroll
    for (int s = 0; s < 8; ++s) sj += xv[s];
    sj *= 0.125f;
    red[t] = sj * sj;
    __syncthreads();
    for (int st = 64; st > 0; st >>= 1) { if (t < st) red[t] += red[t + st]; __syncthreads(); }
    float sq = red[0];
    float vfac = sq / ((1.f + sq) * (sq + 1e-8f));
    float vj = vfac * sj;
#pragma unroll
    for (int s = 0; s < 8; ++s) redp[s][t] = xv[s] * vj;
    __syncthreads();
    for (int st = 64; st > 0; st >>= 1) {
        if (t < st) {
#pragma unroll
            for (int s = 0; s < 8; ++s) redp[s][t] += redp[s][t + st];
        }
        __syncthreads();
    }
    float bv[8], bmax = -1e30f;
#pragma unroll
    for (int s = 0; s < 8; ++s) { bv[s] = redp[s][0]; bmax = fmaxf(bmax, bv[s]); }
    float esum = 0.f;
#pragma unroll
    for (int s = 0; s < 8; ++s) { bv[s] = __expf(bv[s] - bmax); esum += bv[s]; }
    float cinv = 1.f / esum;
    float sj2 = 0.f;
#pragma unroll
    for (int s = 0; s < 8; ++s) sj2 += bv[s] * xv[s];
    sj2 *= cinv;
    __syncthreads();
    red[t] = sj2 * sj2;
    __syncthreads();
    for (int st = 64; st > 0; st >>= 1) { if (t < st) red[t] += red[t + st]; __syncthreads(); }
    float sq2 = red[0];
    float vfac2 = sq2 / ((1.f + sq2) * (sq2 + 1e-8f));
    xB[((size_t)n * 8 + j) * TC_LN + t] = vfac2 * sj2;
}

// ---------------------------------------------------------------------------
// K4a: Cell_A conv (R8 tuning: unroll 1 both loops, launch_bounds(256,4))
__global__ __launch_bounds__(256, 4) void k_cellA_conv(
    const float* __restrict__ xs, const float* __restrict__ wA, const float* __restrict__ bA,
    float* __restrict__ xa, int n0)
{
    const int lc = blockIdx.x * 64;
    const int nrel = blockIdx.y;
    const int n = n0 + nrel;
    const int tid = threadIdx.x;
    __shared__ float xl[64][68];
    __shared__ float wl[64 * 24];
    __shared__ float bl[64];
    for (int i = tid; i < 64 * 24; i += 256) wl[i] = wA[i];
    if (tid < 64) bl[tid] = bA[tid];
    const float* xsn = xs + (size_t)n * (TC_K * TC_L);
    for (int i = tid; i < 64 * 66; i += 256) {
        int k = i / 66, c = i - k * 66;
        int gl = lc + c - 1;
        xl[k][c] = (gl >= 0 && gl < TC_L) ? xsn[k * TC_L + gl] : 0.f;
    }
    __syncthreads();

    const int strip = tid & 15;
    const int g = tid >> 4;
    const int l0 = strip * 4;
    float* xab = xa + (size_t)nrel * 64 * 8192;

#pragma unroll 1
    for (int oi = 0; oi < 4; ++oi) {
        const int o = g * 4 + oi;
        float w[24];
#pragma unroll
        for (int i = 0; i < 24; ++i) w[i] = wl[o * 24 + i];
        const float bias = bl[o];
#pragma unroll 1
        for (int p = 0; p < 8; ++p) {
            float a0 = bias, a1 = bias, a2 = bias, a3 = bias;
#pragma unroll
            for (int dh = 0; dh < 8; ++dh) {
                const float* row = &xl[p * 8 + dh][l0];
                float4 va = *(const float4*)row;
                float2 vb = *(const float2*)(row + 4);
                float w0 = w[dh * 3], w1 = w[dh * 3 + 1], w2 = w[dh * 3 + 2];
                a0 = fmaf(w0, va.x, a0); a0 = fmaf(w1, va.y, a0); a0 = fmaf(w2, va.z, a0);
                a1 = fmaf(w0, va.y, a1); a1 = fmaf(w1, va.z, a1); a1 = fmaf(w2, va.w, a1);
                a2 = fmaf(w0, va.z, a2); a2 = fmaf(w1, va.w, a2); a2 = fmaf(w2, vb.x, a2);
                a3 = fmaf(w0, va.w, a3); a3 = fmaf(w1, vb.x, a3); a3 = fmaf(w2, vb.y, a3);
            }
            *(float4*)&xab[(size_t)o * 8192 + p * TC_L + lc + l0] = make_float4(a0, a1, a2, a3);
        }
    }
}

// ---------------------------------------------------------------------------
// K4b: routing over p from xa; writes bf16 a_bf directly. grid (o=64, 32 n)
__global__ __launch_bounds__(256) void k_cellA_route(
    const float* __restrict__ xa, unsigned short* __restrict__ a_bf, int n0)
{
    const int o = blockIdx.x;
    const int nrel = blockIdx.y;
    const int n = n0 + nrel;
    const int tid = threadIdx.x;
    const int l0 = tid * 4;
    const float* base = xa + ((size_t)nrel * 64 + o) * 8192;

    float xrv[8][4];
#pragma unroll
    for (int p = 0; p < 8; ++p) {
        float4 v = *(const float4*)&base[p * TC_L + l0];
        xrv[p][0] = v.x; xrv[p][1] = v.y; xrv[p][2] = v.z; xrv[p][3] = v.w;
    }

    __shared__ float red[256];
    __shared__ float redp[8][257];

    float sjv[4];
    float part = 0.f;
#pragma unroll
    for (int jj = 0; jj < 4; ++jj) {
        float sv = 0.f;
#pragma unroll
        for (int p = 0; p < 8; ++p) sv += xrv[p][jj];
        sv *= 0.125f;
        sjv[jj] = sv;
        part += sv * sv;
    }
    red[tid] = part;
    __syncthreads();
    for (int st = 128; st > 0; st >>= 1) { if (tid < st) red[tid] += red[tid + st]; __syncthreads(); }
    float sq = red[0];
    float vfac = sq / ((1.f + sq) * (sq + 1e-8f));
    float bp[8] = {};
#pragma unroll
    for (int jj = 0; jj < 4; ++jj) {
        float vj = vfac * sjv[jj];
#pragma unroll
        for (int p = 0; p < 8; ++p) bp[p] += xrv[p][jj] * vj;
    }
#pragma unroll
    for (int p = 0; p < 8; ++p) redp[p][tid] = bp[p];
    __syncthreads();
    for (int st = 128; st > 0; st >>= 1) {
        if (tid < st) {
#pragma unroll
            for (int p = 0; p < 8; ++p) redp[p][tid] += redp[p][tid + st];
        }
        __syncthreads();
    }
    float bv[8], bmax = -1e30f;
#pragma unroll
    for (int p = 0; p < 8; ++p) { bv[p] = redp[p][0]; bmax = fmaxf(bmax, bv[p]); }
    float esum = 0.f;
#pragma unroll
    for (int p = 0; p < 8; ++p) { bv[p] = __expf(bv[p] - bmax); esum += bv[p]; }
    float cinv = 1.f / esum;
    float sj2[4]; float part2 = 0.f;
#pragma unroll
    for (int jj = 0; jj < 4; ++jj) {
        float sv = 0.f;
#pragma unroll
        for (int p = 0; p < 8; ++p) sv += bv[p] * xrv[p][jj];
        sv *= cinv;
        sj2[jj] = sv;
        part2 += sv * sv;
    }
    __syncthreads();
    red[tid] = part2;
    __syncthreads();
    for (int st = 128; st > 0; st >>= 1) { if (tid < st) red[tid] += red[tid + st]; __syncthreads(); }
    float sq2 = red[0];
    float vfac2 = sq2 / ((1.f + sq2) * (sq2 + 1e-8f));
    short4v r;
    r[0] = (short)f2bf(vfac2 * sj2[0]);
    r[1] = (short)f2bf(vfac2 * sj2[1]);
    r[2] = (short)f2bf(vfac2 * sj2[2]);
    r[3] = (short)f2bf(vfac2 * sj2[3]);
    *(short4v*)&a_bf[(size_t)n * 65536 + o * 1024 + l0] = r;
}

// ---------------------------------------------------------------------------
// K4 (fallback): fused Cell_A — used only if ws too small for xa. Writes a_bf.
__global__ __launch_bounds__(256, 4) void k_cellA(
    const float* __restrict__ xs, const float* __restrict__ wA, const float* __restrict__ bA,
    unsigned short* __restrict__ a_bf)
{
    const int o = blockIdx.x;
    const int n = blockIdx.y;
    const int tid = threadIdx.x;
    const int l0 = tid * 4;

    float w[24];
#pragma unroll
    for (int i = 0; i < 24; ++i) w[i] = wA[o * 24 + i];
    const float bias = bA[o];

    const float* xsn = xs + (size_t)n * TC_K * TC_L;
    float xrv[8][4];
#pragma unroll 1
    for (int p = 0; p < 8; ++p) {
        float a0 = bias, a1 = bias, a2 = bias, a3 = bias;
#pragma unroll
        for (int dh = 0; dh < 8; ++dh) {
            const float* row = xsn + (p * 8 + dh) * TC_L;
            float4 vm = *(const float4*)&row[l0];
            float vl = (l0 > 0) ? row[l0 - 1] : 0.f;
            float vr = (l0 + 4 < TC_L) ? row[l0 + 4] : 0.f;
            float w0 = w[dh * 3 + 0], w1 = w[dh * 3 + 1], w2 = w[dh * 3 + 2];
            a0 = fmaf(w0, vl,   a0); a0 = fmaf(w1, vm.x, a0); a0 = fmaf(w2, vm.y, a0);
            a1 = fmaf(w0, vm.x, a1); a1 = fmaf(w1, vm.y, a1); a1 = fmaf(w2, vm.z, a1);
            a2 = fmaf(w0, vm.y, a2); a2 = fmaf(w1, vm.z, a2); a2 = fmaf(w2, vm.w, a2);
            a3 = fmaf(w0, vm.z, a3); a3 = fmaf(w1, vm.w, a3); a3 = fmaf(w2, vr,   a3);
        }
        xrv[p][0] = a0; xrv[p][1] = a1; xrv[p][2] = a2; xrv[p][3] = a3;
    }

    __shared__ float red[256];
    __shared__ float redp[8][257];

    float sjv[4];
    float part = 0.f;
#pragma unroll
    for (int jj = 0; jj < 4; ++jj) {
        float sv = 0.f;
#pragma unroll
        for (int p = 0; p < 8; ++p) sv += xrv[p][jj];
        sv *= 0.125f;
        sjv[jj] = sv;
        part += sv * sv;
    }
    red[tid] = part;
    __syncthreads();
    for (int st = 128; st > 0; st >>= 1) { if (tid < st) red[tid] += red[tid + st]; __syncthreads(); }
    float sq = red[0];
    float vfac = sq / ((1.f + sq) * (sq + 1e-8f));
    float bp[8] = {};
#pragma unroll
    for (int jj = 0; jj < 4; ++jj) {
        float vj = vfac * sjv[jj];
#pragma unroll
        for (int p = 0; p < 8; ++p) bp[p] += xrv[p][jj] * vj;
    }
#pragma unroll
    for (int p = 0; p < 8; ++p) redp[p][tid] = bp[p];
    __syncthreads();
    for (int st = 128; st > 0; st >>= 1) {
        if (tid < st) {
#pragma unroll
            for (int p = 0; p < 8; ++p) redp[p][tid] += redp[p][tid + st];
        }
        __syncthreads();
    }
    float bv[8], bmax = -1e30f;
#pragma unroll
    for (int p = 0; p < 8; ++p) { bv[p] = redp[p][0]; bmax = fmaxf(bmax, bv[p]); }
    float esum = 0.f;
#pragma unroll
    for (int p = 0; p < 8; ++p) { bv[p] = __expf(bv[p] - bmax); esum += bv[p]; }
    float cinv = 1.f / esum;
    float sj2[4]; float part2 = 0.f;
#pragma unroll
    for (int jj = 0; jj < 4; ++jj) {
        float sv = 0.f;
#pragma unroll
        for (int p = 0; p < 8; ++p) sv += bv[p] * xrv[p][jj];
        sv *= cinv;
        sj2[jj] = sv;
        part2 += sv * sv;
    }
    __syncthreads();
    red[tid] = part2;
    __syncthreads();
    for (int st = 128; st > 0; st >>= 1) { if (tid < st) red[tid] += red[tid + st]; __syncthreads(); }
    float sq2 = red[0];
    float vfac2 = sq2 / ((1.f + sq2) * (sq2 + 1e-8f));
    short4v r;
    r[0] = (short)f2bf(vfac2 * sj2[0]);
    r[1] = (short)f2bf(vfac2 * sj2[1]);
    r[2] = (short)f2bf(vfac2 * sj2[2]);
    r[3] = (short)f2bf(vfac2 * sj2[3]);
    *(short4v*)&a_bf[(size_t)n * 65536 + o * 1024 + l0] = r;
}

// ---------------------------------------------------------------------------
// K6pre-B: transpose-convert W[kc][d][o] (d<8192) -> wt[kc][o][8192] bf16.
__global__ __launch_bounds__(256) void k_cvtW(
    const float* __restrict__ W, unsigned short* __restrict__ wt)
{
    const int dc = blockIdx.x * 512;
    const int kc = blockIdx.y;
    const int tid = threadIdx.x;
    __shared__ unsigned short ldsT[16][544];
    for (int i = tid; i < 8192; i += 256) {
        int dl = i >> 4, o = i & 15;
        ldsT[o][dl] = f2bf(W[((size_t)kc * TC_DCAT + dc + dl) * 16 + o]);
    }
    __syncthreads();
    for (int i = tid; i < 8192; i += 256) {
        int o = i >> 9, dl = i & 511;
        wt[((size_t)kc * 16 + o) * 8192 + dc + dl] = ldsT[o][dl];
    }
}

// ---------------------------------------------------------------------------
// K6a: MFMA DigitCaps GEMM. u16x16 tile: rows=(2n x 8c), cols=16 o.
// grid 1280 = 32 npairs x 10 kc x 4 ksplits (XCD-grouped by npair), 64 thr.
__global__ __launch_bounds__(64) void k_digit_mfma(
    const unsigned short* __restrict__ a_bf, const unsigned short* __restrict__ wt,
    float* __restrict__ upart)
{
    const int bid = blockIdx.x;                    // 0..1279
    const int swz = (bid & 7) * 160 + (bid >> 3);  // bijective (1280 % 8 == 0)
    const int npair = swz / 40;                    // 0..31 (XCD-local grouping)
    const int r = swz - npair * 40;
    const int kc = r >> 2;
    const int ks = r & 3;

    const int lane = threadIdx.x;
    const int row  = lane & 15;        // A row = (nn,c); B col = o
    const int kgrp = lane >> 4;        // k-group: k = kgrp*8 + j
    const int nn = row >> 3, c = row & 7;

    const unsigned short* ap = a_bf + (((size_t)(npair * 2 + nn) * 8 + c) * 8192)
                                    + ks * 2048 + kgrp * 8;
    const unsigned short* bp = wt + (((size_t)kc * 16 + row) * 8192)
                                  + ks * 2048 + kgrp * 8;

    f32x4 acc = {0.f, 0.f, 0.f, 0.f};
#pragma unroll 8
    for (int m = 0; m < 64; ++m) {
        short8v av = *(const short8v*)(ap + m * 32);
        short8v bv = *(const short8v*)(bp + m * 32);
        acc = __builtin_amdgcn_mfma_f32_16x16x32_bf16(av, bv, acc, 0, 0, 0);
    }

    const int colo = lane & 15;
    const int rbase = (lane >> 4) * 4;
#pragma unroll
    for (int j = 0; j < 4; ++j) {
        int rw = rbase + j;
        int nn2 = rw >> 3, c2 = rw & 7;
        upart[((((size_t)(npair * 2 + nn2) * TC_NCLS + kc) * 5 + ks) * 128)
              + c2 * 16 + colo] = acc[j];
    }
}

// ---------------------------------------------------------------------------
// K6a-tail: fp32 xB segment (d 8192..8319) -> upart slot 4.
__global__ __launch_bounds__(256) void k_digit_tail(
    const float* __restrict__ xB, const float* __restrict__ W,
    float* __restrict__ upart)
{
    const int kc = blockIdx.x, n = blockIdx.y;
    const int tid = threadIdx.x;
    const int lane = tid & 63;
    const int oq = tid >> 6;
    const float* Wk = W + (size_t)kc * (TC_DCAT * 16);
    const float* xc = xB + (size_t)n * 1024;

    float acc[8][4] = {};
#pragma unroll
    for (int it = 0; it < 2; ++it) {
        int dd = it * 64 + lane;
        float4 wv = *(const float4*)&Wk[(size_t)(8192 + dd) * 16 + oq * 4];
#pragma unroll
        for (int c = 0; c < 8; ++c) {
            float xv = xc[c * 128 + dd];
            acc[c][0] = fmaf(wv.x, xv, acc[c][0]);
            acc[c][1] = fmaf(wv.y, xv, acc[c][1]);
            acc[c][2] = fmaf(wv.z, xv, acc[c][2]);
            acc[c][3] = fmaf(wv.w, xv, acc[c][3]);
        }
    }
#pragma unroll
    for (int c = 0; c < 8; ++c) {
#pragma unroll
        for (int j = 0; j < 4; ++j) {
            float v = acc[c][j];
#pragma unroll
            for (int s = 32; s > 0; s >>= 1) v += __shfl_xor(v, s, 64);
            acc[c][j] = v;
        }
    }
    if (lane == 0) {
        float* up = upart + ((((size_t)n * TC_NCLS + kc) * 5 + 4) * 128);
#pragma unroll
        for (int c = 0; c < 8; ++c)
            *(float4*)&up[c * 16 + oq * 4] =
                make_float4(acc[c][0], acc[c][1], acc[c][2], acc[c][3]);
    }
}

// ---------------------------------------------------------------------------
// K6b: sum partials (alpha for slots 0-3, beta for slot 4) + routing -> out.
__global__ __launch_bounds__(64) void k_digit_route(
    const float* __restrict__ upart, const float* __restrict__ alphap,
    const float* __restrict__ betap, float* __restrict__ out)
{
    const int kc = blockIdx.x, n = blockIdx.y;
    const int tid = threadIdx.x;
    const float alpha = alphap[0], beta = betap[0];
    __shared__ float ul[8][16];
    __shared__ float sjo[16];
    __shared__ float bc[8];
    __shared__ float fac[1];

    const float* up = upart + (((size_t)n * TC_NCLS + kc) * 5) * 128;
    for (int i = tid; i < 128; i += 64) {
        float sa = up[0 * 128 + i] + up[1 * 128 + i] + up[2 * 128 + i] + up[3 * 128 + i];
        ul[i >> 4][i & 15] = alpha * sa + beta * up[4 * 128 + i];
    }
    __syncthreads();

    if (tid < 16) {
        float sv = 0.f;
#pragma unroll
        for (int c = 0; c < 8; ++c) sv += ul[c][tid];
        sjo[tid] = sv * 0.125f;
    }
    __syncthreads();
    if (tid == 0) {
        float sq = 0.f;
#pragma unroll
        for (int oo = 0; oo < 16; ++oo) sq += sjo[oo] * sjo[oo];
        fac[0] = sq / ((1.f + sq) * (sq + 1e-8f));
    }
    __syncthreads();
    if (tid < 8) {
        float vf = fac[0];
        float sv = 0.f;
#pragma unroll
        for (int oo = 0; oo < 16; ++oo) sv += ul[tid][oo] * (vf * sjo[oo]);
        bc[tid] = sv;
    }
    __syncthreads();
    if (tid < 16) {
        float bmax = -1e30f;
#pragma unroll
        for (int c = 0; c < 8; ++c) bmax = fmaxf(bmax, bc[c]);
        float e[8]; float es = 0.f;
#pragma unroll
        for (int c = 0; c < 8; ++c) { e[c] = __expf(bc[c] - bmax); es += e[c]; }
        float inv = 1.f / es;
        float sv = 0.f;
#pragma unroll
        for (int c = 0; c < 8; ++c) sv += e[c] * inv * ul[c][tid];
        sjo[tid] = sv;
    }
    __syncthreads();
    if (tid == 0) {
        float sq = 0.f;
#pragma unroll
        for (int oo = 0; oo < 16; ++oo) sq += sjo[oo] * sjo[oo];
        fac[0] = sq / ((1.f + sq) * (sq + 1e-8f));
    }
    __syncthreads();
    if (tid < 16) {
        out[((size_t)n * TC_NCLS + kc) * 16 + tid] = fac[0] * sjo[tid];
    }
}

// ---------------------------------------------------------------------------
extern "C" void kernel_launch(void* const* d_in, const int* in_sizes, int n_in,
                              void* d_out, int out_size, void* d_ws, size_t ws_size,
                              hipStream_t stream) {
    const float* X   = (const float*)d_in[0];
    const float* w1  = (const float*)d_in[1];
    const float* w2  = (const float*)d_in[2];
    const float* wA  = (const float*)d_in[3];
    const float* bA  = (const float*)d_in[4];
    const float* wB  = (const float*)d_in[5];
    const float* bB  = (const float*)d_in[6];
    const float* wk  = (const float*)d_in[7];
    const float* bk  = (const float*)d_in[8];
    const float* Wd  = (const float*)d_in[9];
    const float* alphap = (const float*)d_in[10];
    const float* betap  = (const float*)d_in[11];
    float* out = (float*)d_out;

    float* ws  = (float*)d_ws;
    float* x   = ws;                     // [64][64][1024] = 4194304
    float* xs  = ws + 4194304;           // [64][64][1024] = 4194304
    float* xbS = ws + 8388608;           // [64][8][8][128] = 65536
    float* xB  = ws + 8454144;           // [64][8][128] region = 65536
    float* w2r = ws + 8519680;           // 20480 floats (psi_m repacked weights)
    float* xa  = ws + 8540160;           // [32][64][8][1024] = 16777216 (64MB, reused x2)
    // x region dead after cellB_conv -> Cell_A routing writes bf16 a_bf there:
    unsigned short* a_bf = (unsigned short*)x;      // 4194304 ushorts
    // xs region dead after cellA_conv -> digit stage scratch:
    float* upart = xs;                              // 409600 floats
    unsigned short* wt_bf = (unsigned short*)(xs + 2621440); // 1310720 ushorts

    const size_t need = (size_t)(8540160 + 16777216) * sizeof(float);
    const bool split = ws_size >= need;

    k_conv1<<<dim3(64, 64), 256, 0, stream>>>(X, w1, x);
    k_repack_w2<<<dim3(80), 256, 0, stream>>>(w2, w2r);
    k_psim<<<dim3(2048), 256, 0, stream>>>(x, w2r, xs);
    k_squash_rows<<<dim3(4096), 256, 0, stream>>>(xs);
    k_cellB_conv<<<dim3(8, 64), 256, 0, stream>>>(x, wB, bB, wk, bk, xbS);
    k_routeB<<<dim3(8, 64), 128, 0, stream>>>(xbS, xB);
    if (split) {
        for (int g = 0; g < 2; ++g) {
            k_cellA_conv<<<dim3(16, 32), 256, 0, stream>>>(xs, wA, bA, xa, g * 32);
            k_cellA_route<<<dim3(64, 32), 256, 0, stream>>>(xa, a_bf, g * 32);
        }
    } else {
        k_cellA<<<dim3(64, 64), 256, 0, stream>>>(xs, wA, bA, a_bf);
    }
    // digit stage (xs region reused)
    k_cvtW<<<dim3(16, 10), 256, 0, stream>>>(Wd, wt_bf);
    k_digit_mfma<<<dim3(1280), 64, 0, stream>>>(a_bf, wt_bf, upart);
    k_digit_tail<<<dim3(10, 64), 256, 0, stream>>>(xB, Wd, upart);
    k_digit_route<<<dim3(10, 64), 64, 0, stream>>>(upart, alphap, betap, out);
}

// Round 16
// 213.029 us; speedup vs baseline: 1.1867x; 1.1867x over previous
//
#include <hip/hip_runtime.h>

#define TC_L    1024
#define TC_K    64
#define TC_LN   128
#define TC_NCLS 10
#define TC_DCAT 8320

typedef __attribute__((ext_vector_type(8))) short short8v;
typedef __attribute__((ext_vector_type(4))) short short4v;
typedef __attribute__((ext_vector_type(4))) float f32x4;

__device__ __forceinline__ unsigned short f2bf(float f) {
    unsigned int u = __float_as_uint(f);
    u = (u + 0x7FFFu + ((u >> 16) & 1u)) >> 16;
    return (unsigned short)u;
}
__device__ __forceinline__ float bf2f(unsigned short u) {
    return __uint_as_float(((unsigned int)u) << 16);
}

// ---------------------------------------------------------------------------
// K1: conv1  x[n,k,l] = sum_t w1[k,t] * X[n, l-4+t]   (pad 4)
__global__ __launch_bounds__(256) void k_conv1(
    const float* __restrict__ X, const float* __restrict__ w1, float* __restrict__ x)
{
    const int k = blockIdx.x, n = blockIdx.y;
    float w[9];
#pragma unroll
    for (int t = 0; t < 9; ++t) w[t] = w1[k * 9 + t];
    const float* xin = X + n * TC_L;
    float* out = x + (n * TC_K + k) * TC_L;
    for (int l = threadIdx.x; l < TC_L; l += 256) {
        float acc = 0.f;
#pragma unroll
        for (int t = 0; t < 9; ++t) {
            int idx = l - 4 + t;
            float v = (idx >= 0 && idx < TC_L) ? xin[idx] : 0.f;
            acc = fmaf(w[t], v, acc);
        }
        out[l] = acc;
    }
}

// ---------------------------------------------------------------------------
// K2pre (R11 layout): repack psi_m weights per-wave-contiguous:
// w2r[og(16)][ic(64)][t(5)][q(4)], og = ocb*4+ocg, oc = og*4+q.
__global__ __launch_bounds__(256) void k_repack_w2(
    const float* __restrict__ w2, float* __restrict__ w2r)
{
    int i = blockIdx.x * 256 + threadIdx.x;   // 20480 total
    if (i < 20480) {
        int q = i & 3;
        int t = (i >> 2) % 5;
        int ic = (i / 20) & 63;
        int og = i / 1280;
        w2r[i] = w2[(size_t)(og * 4 + q) * 320 + ic * 5 + t];
    }
}

// ---------------------------------------------------------------------------
// K2 (R13 config, known-best 43us): psi_m conv, NO LDS, 4 oc/thread +
// XCD-aware swizzle: flat grid 1024; all 4 ocb-sharers of one (lc,n)
// x-slice land on ONE XCD.
__global__ __launch_bounds__(256) void k_psim(
    const float* __restrict__ x, const float* __restrict__ w2r, float* __restrict__ xs)
{
    const int bid = blockIdx.x;                     // 0..1023
    const int swz = (bid & 7) * 128 + (bid >> 3);   // bijective (1024 % 8 == 0)
    const int ocb = swz & 3;                        // 0..3 -> oc base = ocb*16
    const int lcq = (swz >> 2) & 3;
    const int n   = swz >> 4;                       // 0..63
    const int lc  = lcq * 256;
    const int tid = threadIdx.x;
    const int lgrp = tid & 63;
    const int ocg  = __builtin_amdgcn_readfirstlane(tid >> 6);   // wave-uniform
    const int l0   = lgrp * 4;
    const bool lpad = (lc == 0) && (lgrp == 0);
    const bool rpad = (lc == 768) && (lgrp == 63);

    const float* __restrict__ wv = w2r + (size_t)(ocb * 4 + ocg) * 1280; // uniform
    float acc[4][4] = {};
    const float* xn = x + (size_t)n * TC_K * TC_L;
#pragma unroll 4
    for (int ic = 0; ic < 64; ++ic) {
        const float* row = xn + ic * TC_L + lc;
        float4 va = *(const float4*)&row[l0];                    // l0..l0+3
        float2 vh = *(const float2*)&row[lpad ? l0 : (l0 - 2)];  // l0-2, l0-1
        float2 vb = *(const float2*)&row[l0 + 4];                // l0+4, l0+5
        if (lpad) { vh.x = 0.f; vh.y = 0.f; }
        if (rpad) { vb.x = 0.f; vb.y = 0.f; }
        float v[8] = {vh.x, vh.y, va.x, va.y, va.z, va.w, vb.x, vb.y};
        const float* wp = wv + ic * 20;                          // uniform
#pragma unroll
        for (int t = 0; t < 5; ++t) {
            float4 wa = *(const float4*)&wp[t * 4];              // -> s_load_dwordx4
            float wq[4] = {wa.x, wa.y, wa.z, wa.w};
#pragma unroll
            for (int q = 0; q < 4; ++q) {
#pragma unroll
                for (int j = 0; j < 4; ++j)
                    acc[q][j] = fmaf(wq[q], v[j + t], acc[q][j]);
            }
        }
    }
#pragma unroll
    for (int q = 0; q < 4; ++q) {
        int oc = ocb * 16 + ocg * 4 + q;
        *(float4*)&xs[((size_t)n * TC_K + oc) * TC_L + lc + l0] =
            make_float4(acc[q][0], acc[q][1], acc[q][2], acc[q][3]);
    }
}

// ---------------------------------------------------------------------------
// K3: squash each row of 1024 in place
__global__ __launch_bounds__(256) void k_squash_rows(float* __restrict__ xs)
{
    const int row = blockIdx.x;
    float* p = xs + (size_t)row * TC_L;
    const int tid = threadIdx.x;
    float4 v = *(const float4*)&p[tid * 4];
    float part = v.x * v.x + v.y * v.y + v.z * v.z + v.w * v.w;
    __shared__ float red[256];
    red[tid] = part;
    __syncthreads();
    for (int s = 128; s > 0; s >>= 1) {
        if (tid < s) red[tid] += red[tid + s];
        __syncthreads();
    }
    float sq = red[0];
    float scale = sq / ((1.f + sq) * (sq + 1e-8f));
    v.x *= scale; v.y *= scale; v.z *= scale; v.w *= scale;
    *(float4*)&p[tid * 4] = v;
}

// ---------------------------------------------------------------------------
// K5a: Cell_B convs + bias + squash(last=128) -> xbS[n][j=8][s=8][128]
__global__ __launch_bounds__(256) void k_cellB_conv(
    const float* __restrict__ x, const float* __restrict__ wB, const float* __restrict__ bB,
    const float* __restrict__ wk, const float* __restrict__ bk, float* __restrict__ xbS)
{
    const int s = blockIdx.x;
    const int n = blockIdx.y;
    __shared__ float wBl[64 * 64];
    __shared__ float wkl[8 * 320];
    __shared__ float xb1[64][132];
    __shared__ float redq[8][33];
    const int tid = threadIdx.x;
    for (int i = tid; i < 4096; i += 256) wBl[i] = wB[i];
    for (int i = tid; i < 2560; i += 256) wkl[i] = wk[i];
    for (int i = tid; i < 64; i += 256) {
        xb1[i][0] = xb1[i][1] = xb1[i][130] = xb1[i][131] = 0.f;
    }
    __syncthreads();

    {
        const int t0  = (tid & 31) * 4;
        const int chg = tid >> 5;
        float acc[8][4] = {};
        const float* xbase = x + (size_t)n * TC_K * TC_L + s * TC_LN + t0;
        for (int k = 0; k < 64; ++k) {
            float4 xv = *(const float4*)&xbase[(size_t)k * TC_L];
            float v0 = xv.x, v1 = xv.y, v2 = xv.z, v3 = xv.w;
#pragma unroll
            for (int cc = 0; cc < 8; ++cc) {
                float w = wBl[(chg * 8 + cc) * 64 + k];
                acc[cc][0] = fmaf(w, v0, acc[cc][0]);
                acc[cc][1] = fmaf(w, v1, acc[cc][1]);
                acc[cc][2] = fmaf(w, v2, acc[cc][2]);
                acc[cc][3] = fmaf(w, v3, acc[cc][3]);
            }
        }
#pragma unroll
        for (int cc = 0; cc < 8; ++cc) {
            int ch = chg * 8 + cc;
            float b = bB[ch];
            xb1[ch][2 + t0 + 0] = acc[cc][0] + b;
            xb1[ch][2 + t0 + 1] = acc[cc][1] + b;
            xb1[ch][2 + t0 + 2] = acc[cc][2] + b;
            xb1[ch][2 + t0 + 3] = acc[cc][3] + b;
        }
    }
    __syncthreads();

    {
        const int t0 = (tid & 31) * 4;
        const int j  = tid >> 5;
        float acc[4] = {};
        for (int ch = 0; ch < 64; ++ch) {
            float4 va = *(const float4*)&xb1[ch][t0];
            float4 vb = *(const float4*)&xb1[ch][t0 + 4];
            float v[8] = {va.x, va.y, va.z, va.w, vb.x, vb.y, vb.z, vb.w};
            const float* wp = &wkl[j * 320 + ch * 5];
#pragma unroll
            for (int dw = 0; dw < 5; ++dw) {
                float w = wp[dw];
#pragma unroll
                for (int q = 0; q < 4; ++q) acc[q] = fmaf(w, v[q + dw], acc[q]);
            }
        }
        float b = bk[j];
#pragma unroll
        for (int q = 0; q < 4; ++q) acc[q] += b;
        float part = acc[0]*acc[0] + acc[1]*acc[1] + acc[2]*acc[2] + acc[3]*acc[3];
        redq[j][tid & 31] = part;
        __syncthreads();
        for (int st = 16; st > 0; st >>= 1) {
            if ((tid & 31) < st) redq[j][tid & 31] += redq[j][(tid & 31) + st];
            __syncthreads();
        }
        float sq = redq[j][0];
        float scale = sq / ((1.f + sq) * (sq + 1e-8f));
        float* outp = xbS + (((size_t)n * 8 + j) * 8 + s) * TC_LN + t0;
        *(float4*)outp = make_float4(acc[0]*scale, acc[1]*scale, acc[2]*scale, acc[3]*scale);
    }
}

// ---------------------------------------------------------------------------
// K5b: routing over s for Cell_B -> xB[n][j][t]
__global__ __launch_bounds__(128) void k_routeB(
    const float* __restrict__ xbS, float* __restrict__ xB)
{
    const int j = blockIdx.x, n = blockIdx.y;
    const int t = threadIdx.x;
    float xv[8];
    const float* base = xbS + ((size_t)n * 8 + j) * 8 * TC_LN;
#pragma unroll
    for (int s = 0; s < 8; ++s) xv[s] = base[s * TC_LN + t];

    __shared__ float red[128];
    __shared__ float redp[8][129];

    float sj = 0.f;
#pragma unroll
    for (int s = 0; s < 8; ++s) sj += xv[s];
    sj *= 0.125f;
    red[t] = sj * sj;
    __syncthreads();
    for (int st = 64; st > 0; st >>= 1) { if (t < st) red[t] += red[t + st]; __syncthreads(); }
    float sq = red[0];
    float vfac = sq / ((1.f + sq) * (sq + 1e-8f));
    float vj = vfac * sj;
#pragma unroll
    for (int s = 0; s < 8; ++s) redp[s][t] = xv[s] * vj;
    __syncthreads();
    for (int st = 64; st > 0; st >>= 1) {
        if (t < st) {
#pragma unroll
            for (int s = 0; s < 8; ++s) redp[s][t] += redp[s][t + st];
        }
        __syncthreads();
    }
    float bv[8], bmax = -1e30f;
#pragma unroll
    for (int s = 0; s < 8; ++s) { bv[s] = redp[s][0]; bmax = fmaxf(bmax, bv[s]); }
    float esum = 0.f;
#pragma unroll
    for (int s = 0; s < 8; ++s) { bv[s] = __expf(bv[s] - bmax); esum += bv[s]; }
    float cinv = 1.f / esum;
    float sj2 = 0.f;
#pragma unroll
    for (int s = 0; s < 8; ++s) sj2 += bv[s] * xv[s];
    sj2 *= cinv;
    __syncthreads();
    red[t] = sj2 * sj2;
    __syncthreads();
    for (int st = 64; st > 0; st >>= 1) { if (t < st) red[t] += red[t + st]; __syncthreads(); }
    float sq2 = red[0];
    float vfac2 = sq2 / ((1.f + sq2) * (sq2 + 1e-8f));
    xB[((size_t)n * 8 + j) * TC_LN + t] = vfac2 * sj2;
}

// ---------------------------------------------------------------------------
// K4a (R15): Cell_A conv; xa now stored as bf16 (halves xa write traffic).
__global__ __launch_bounds__(256, 4) void k_cellA_conv(
    const float* __restrict__ xs, const float* __restrict__ wA, const float* __restrict__ bA,
    unsigned short* __restrict__ xa, int n0)
{
    const int lc = blockIdx.x * 64;
    const int nrel = blockIdx.y;
    const int n = n0 + nrel;
    const int tid = threadIdx.x;
    __shared__ float xl[64][68];
    __shared__ float wl[64 * 24];
    __shared__ float bl[64];
    for (int i = tid; i < 64 * 24; i += 256) wl[i] = wA[i];
    if (tid < 64) bl[tid] = bA[tid];
    const float* xsn = xs + (size_t)n * (TC_K * TC_L);
    for (int i = tid; i < 64 * 66; i += 256) {
        int k = i / 66, c = i - k * 66;
        int gl = lc + c - 1;
        xl[k][c] = (gl >= 0 && gl < TC_L) ? xsn[k * TC_L + gl] : 0.f;
    }
    __syncthreads();

    const int strip = tid & 15;
    const int g = tid >> 4;
    const int l0 = strip * 4;
    unsigned short* xab = xa + (size_t)nrel * 64 * 8192;

#pragma unroll 1
    for (int oi = 0; oi < 4; ++oi) {
        const int o = g * 4 + oi;
        float w[24];
#pragma unroll
        for (int i = 0; i < 24; ++i) w[i] = wl[o * 24 + i];
        const float bias = bl[o];
#pragma unroll 1
        for (int p = 0; p < 8; ++p) {
            float a0 = bias, a1 = bias, a2 = bias, a3 = bias;
#pragma unroll
            for (int dh = 0; dh < 8; ++dh) {
                const float* row = &xl[p * 8 + dh][l0];
                float4 va = *(const float4*)row;
                float2 vb = *(const float2*)(row + 4);
                float w0 = w[dh * 3], w1 = w[dh * 3 + 1], w2 = w[dh * 3 + 2];
                a0 = fmaf(w0, va.x, a0); a0 = fmaf(w1, va.y, a0); a0 = fmaf(w2, va.z, a0);
                a1 = fmaf(w0, va.y, a1); a1 = fmaf(w1, va.z, a1); a1 = fmaf(w2, va.w, a1);
                a2 = fmaf(w0, va.z, a2); a2 = fmaf(w1, va.w, a2); a2 = fmaf(w2, vb.x, a2);
                a3 = fmaf(w0, va.w, a3); a3 = fmaf(w1, vb.x, a3); a3 = fmaf(w2, vb.y, a3);
            }
            short4v r;
            r[0] = (short)f2bf(a0); r[1] = (short)f2bf(a1);
            r[2] = (short)f2bf(a2); r[3] = (short)f2bf(a3);
            *(short4v*)&xab[(size_t)o * 8192 + p * TC_L + lc + l0] = r;
        }
    }
}

// ---------------------------------------------------------------------------
// K4b (R15): routing over p from bf16 xa; writes bf16 a_bf. grid (o=64, 32 n)
__global__ __launch_bounds__(256) void k_cellA_route(
    const unsigned short* __restrict__ xa, unsigned short* __restrict__ a_bf, int n0)
{
    const int o = blockIdx.x;
    const int nrel = blockIdx.y;
    const int n = n0 + nrel;
    const int tid = threadIdx.x;
    const int l0 = tid * 4;
    const unsigned short* base = xa + ((size_t)nrel * 64 + o) * 8192;

    float xrv[8][4];
#pragma unroll
    for (int p = 0; p < 8; ++p) {
        short4v v = *(const short4v*)&base[p * TC_L + l0];
        xrv[p][0] = bf2f((unsigned short)v[0]);
        xrv[p][1] = bf2f((unsigned short)v[1]);
        xrv[p][2] = bf2f((unsigned short)v[2]);
        xrv[p][3] = bf2f((unsigned short)v[3]);
    }

    __shared__ float red[256];
    __shared__ float redp[8][257];

    float sjv[4];
    float part = 0.f;
#pragma unroll
    for (int jj = 0; jj < 4; ++jj) {
        float sv = 0.f;
#pragma unroll
        for (int p = 0; p < 8; ++p) sv += xrv[p][jj];
        sv *= 0.125f;
        sjv[jj] = sv;
        part += sv * sv;
    }
    red[tid] = part;
    __syncthreads();
    for (int st = 128; st > 0; st >>= 1) { if (tid < st) red[tid] += red[tid + st]; __syncthreads(); }
    float sq = red[0];
    float vfac = sq / ((1.f + sq) * (sq + 1e-8f));
    float bp[8] = {};
#pragma unroll
    for (int jj = 0; jj < 4; ++jj) {
        float vj = vfac * sjv[jj];
#pragma unroll
        for (int p = 0; p < 8; ++p) bp[p] += xrv[p][jj] * vj;
    }
#pragma unroll
    for (int p = 0; p < 8; ++p) redp[p][tid] = bp[p];
    __syncthreads();
    for (int st = 128; st > 0; st >>= 1) {
        if (tid < st) {
#pragma unroll
            for (int p = 0; p < 8; ++p) redp[p][tid] += redp[p][tid + st];
        }
        __syncthreads();
    }
    float bv[8], bmax = -1e30f;
#pragma unroll
    for (int p = 0; p < 8; ++p) { bv[p] = redp[p][0]; bmax = fmaxf(bmax, bv[p]); }
    float esum = 0.f;
#pragma unroll
    for (int p = 0; p < 8; ++p) { bv[p] = __expf(bv[p] - bmax); esum += bv[p]; }
    float cinv = 1.f / esum;
    float sj2[4]; float part2 = 0.f;
#pragma unroll
    for (int jj = 0; jj < 4; ++jj) {
        float sv = 0.f;
#pragma unroll
        for (int p = 0; p < 8; ++p) sv += bv[p] * xrv[p][jj];
        sv *= cinv;
        sj2[jj] = sv;
        part2 += sv * sv;
    }
    __syncthreads();
    red[tid] = part2;
    __syncthreads();
    for (int st = 128; st > 0; st >>= 1) { if (tid < st) red[tid] += red[tid + st]; __syncthreads(); }
    float sq2 = red[0];
    float vfac2 = sq2 / ((1.f + sq2) * (sq2 + 1e-8f));
    short4v r;
    r[0] = (short)f2bf(vfac2 * sj2[0]);
    r[1] = (short)f2bf(vfac2 * sj2[1]);
    r[2] = (short)f2bf(vfac2 * sj2[2]);
    r[3] = (short)f2bf(vfac2 * sj2[3]);
    *(short4v*)&a_bf[(size_t)n * 65536 + o * 1024 + l0] = r;
}

// ---------------------------------------------------------------------------
// K4 (fallback): fused Cell_A — used only if ws too small for xa. Writes a_bf.
__global__ __launch_bounds__(256, 4) void k_cellA(
    const float* __restrict__ xs, const float* __restrict__ wA, const float* __restrict__ bA,
    unsigned short* __restrict__ a_bf)
{
    const int o = blockIdx.x;
    const int n = blockIdx.y;
    const int tid = threadIdx.x;
    const int l0 = tid * 4;

    float w[24];
#pragma unroll
    for (int i = 0; i < 24; ++i) w[i] = wA[o * 24 + i];
    const float bias = bA[o];

    const float* xsn = xs + (size_t)n * TC_K * TC_L;
    float xrv[8][4];
#pragma unroll 1
    for (int p = 0; p < 8; ++p) {
        float a0 = bias, a1 = bias, a2 = bias, a3 = bias;
#pragma unroll
        for (int dh = 0; dh < 8; ++dh) {
            const float* row = xsn + (p * 8 + dh) * TC_L;
            float4 vm = *(const float4*)&row[l0];
            float vl = (l0 > 0) ? row[l0 - 1] : 0.f;
            float vr = (l0 + 4 < TC_L) ? row[l0 + 4] : 0.f;
            float w0 = w[dh * 3 + 0], w1 = w[dh * 3 + 1], w2 = w[dh * 3 + 2];
            a0 = fmaf(w0, vl,   a0); a0 = fmaf(w1, vm.x, a0); a0 = fmaf(w2, vm.y, a0);
            a1 = fmaf(w0, vm.x, a1); a1 = fmaf(w1, vm.y, a1); a1 = fmaf(w2, vm.z, a1);
            a2 = fmaf(w0, vm.y, a2); a2 = fmaf(w1, vm.z, a2); a2 = fmaf(w2, vm.w, a2);
            a3 = fmaf(w0, vm.z, a3); a3 = fmaf(w1, vm.w, a3); a3 = fmaf(w2, vr,   a3);
        }
        xrv[p][0] = a0; xrv[p][1] = a1; xrv[p][2] = a2; xrv[p][3] = a3;
    }

    __shared__ float red[256];
    __shared__ float redp[8][257];

    float sjv[4];
    float part = 0.f;
#pragma unroll
    for (int jj = 0; jj < 4; ++jj) {
        float sv = 0.f;
#pragma unroll
        for (int p = 0; p < 8; ++p) sv += xrv[p][jj];
        sv *= 0.125f;
        sjv[jj] = sv;
        part += sv * sv;
    }
    red[tid] = part;
    __syncthreads();
    for (int st = 128; st > 0; st >>= 1) { if (tid < st) red[tid] += red[tid + st]; __syncthreads(); }
    float sq = red[0];
    float vfac = sq / ((1.f + sq) * (sq + 1e-8f));
    float bp[8] = {};
#pragma unroll
    for (int jj = 0; jj < 4; ++jj) {
        float vj = vfac * sjv[jj];
#pragma unroll
        for (int p = 0; p < 8; ++p) bp[p] += xrv[p][jj] * vj;
    }
#pragma unroll
    for (int p = 0; p < 8; ++p) redp[p][tid] = bp[p];
    __syncthreads();
    for (int st = 128; st > 0; st >>= 1) {
        if (tid < st) {
#pragma unroll
            for (int p = 0; p < 8; ++p) redp[p][tid] += redp[p][tid + st];
        }
        __syncthreads();
    }
    float bv[8], bmax = -1e30f;
#pragma unroll
    for (int p = 0; p < 8; ++p) { bv[p] = redp[p][0]; bmax = fmaxf(bmax, bv[p]); }
    float esum = 0.f;
#pragma unroll
    for (int p = 0; p < 8; ++p) { bv[p] = __expf(bv[p] - bmax); esum += bv[p]; }
    float cinv = 1.f / esum;
    float sj2[4]; float part2 = 0.f;
#pragma unroll
    for (int jj = 0; jj < 4; ++jj) {
        float sv = 0.f;
#pragma unroll
        for (int p = 0; p < 8; ++p) sv += bv[p] * xrv[p][jj];
        sv *= cinv;
        sj2[jj] = sv;
        part2 += sv * sv;
    }
    __syncthreads();
    red[tid] = part2;
    __syncthreads();
    for (int st = 128; st > 0; st >>= 1) { if (tid < st) red[tid] += red[tid + st]; __syncthreads(); }
    float sq2 = red[0];
    float vfac2 = sq2 / ((1.f + sq2) * (sq2 + 1e-8f));
    short4v r;
    r[0] = (short)f2bf(vfac2 * sj2[0]);
    r[1] = (short)f2bf(vfac2 * sj2[1]);
    r[2] = (short)f2bf(vfac2 * sj2[2]);
    r[3] = (short)f2bf(vfac2 * sj2[3]);
    *(short4v*)&a_bf[(size_t)n * 65536 + o * 1024 + l0] = r;
}

// ---------------------------------------------------------------------------
// K6pre-B: transpose-convert W[kc][d][o] (d<8192) -> wt[kc][o][8192] bf16.
__global__ __launch_bounds__(256) void k_cvtW(
    const float* __restrict__ W, unsigned short* __restrict__ wt)
{
    const int dc = blockIdx.x * 512;
    const int kc = blockIdx.y;
    const int tid = threadIdx.x;
    __shared__ unsigned short ldsT[16][544];
    for (int i = tid; i < 8192; i += 256) {
        int dl = i >> 4, o = i & 15;
        ldsT[o][dl] = f2bf(W[((size_t)kc * TC_DCAT + dc + dl) * 16 + o]);
    }
    __syncthreads();
    for (int i = tid; i < 8192; i += 256) {
        int o = i >> 9, dl = i & 511;
        wt[((size_t)kc * 16 + o) * 8192 + dc + dl] = ldsT[o][dl];
    }
}

// ---------------------------------------------------------------------------
// K6a: MFMA DigitCaps GEMM. u16x16 tile: rows=(2n x 8c), cols=16 o.
// grid 1280 = 32 npairs x 10 kc x 4 ksplits (XCD-grouped by npair), 64 thr.
__global__ __launch_bounds__(64) void k_digit_mfma(
    const unsigned short* __restrict__ a_bf, const unsigned short* __restrict__ wt,
    float* __restrict__ upart)
{
    const int bid = blockIdx.x;                    // 0..1279
    const int swz = (bid & 7) * 160 + (bid >> 3);  // bijective (1280 % 8 == 0)
    const int npair = swz / 40;                    // 0..31 (XCD-local grouping)
    const int r = swz - npair * 40;
    const int kc = r >> 2;
    const int ks = r & 3;

    const int lane = threadIdx.x;
    const int row  = lane & 15;        // A row = (nn,c); B col = o
    const int kgrp = lane >> 4;        // k-group: k = kgrp*8 + j
    const int nn = row >> 3, c = row & 7;

    const unsigned short* ap = a_bf + (((size_t)(npair * 2 + nn) * 8 + c) * 8192)
                                    + ks * 2048 + kgrp * 8;
    const unsigned short* bp = wt + (((size_t)kc * 16 + row) * 8192)
                                  + ks * 2048 + kgrp * 8;

    f32x4 acc = {0.f, 0.f, 0.f, 0.f};
#pragma unroll 8
    for (int m = 0; m < 64; ++m) {
        short8v av = *(const short8v*)(ap + m * 32);
        short8v bv = *(const short8v*)(bp + m * 32);
        acc = __builtin_amdgcn_mfma_f32_16x16x32_bf16(av, bv, acc, 0, 0, 0);
    }

    const int colo = lane & 15;
    const int rbase = (lane >> 4) * 4;
#pragma unroll
    for (int j = 0; j < 4; ++j) {
        int rw = rbase + j;
        int nn2 = rw >> 3, c2 = rw & 7;
        upart[((((size_t)(npair * 2 + nn2) * TC_NCLS + kc) * 5 + ks) * 128)
              + c2 * 16 + colo] = acc[j];
    }
}

// ---------------------------------------------------------------------------
// K6a-tail: fp32 xB segment (d 8192..8319) -> upart slot 4.
__global__ __launch_bounds__(256) void k_digit_tail(
    const float* __restrict__ xB, const float* __restrict__ W,
    float* __restrict__ upart)
{
    const int kc = blockIdx.x, n = blockIdx.y;
    const int tid = threadIdx.x;
    const int lane = tid & 63;
    const int oq = tid >> 6;
    const float* Wk = W + (size_t)kc * (TC_DCAT * 16);
    const float* xc = xB + (size_t)n * 1024;

    float acc[8][4] = {};
#pragma unroll
    for (int it = 0; it < 2; ++it) {
        int dd = it * 64 + lane;
        float4 wv = *(const float4*)&Wk[(size_t)(8192 + dd) * 16 + oq * 4];
#pragma unroll
        for (int c = 0; c < 8; ++c) {
            float xv = xc[c * 128 + dd];
            acc[c][0] = fmaf(wv.x, xv, acc[c][0]);
            acc[c][1] = fmaf(wv.y, xv, acc[c][1]);
            acc[c][2] = fmaf(wv.z, xv, acc[c][2]);
            acc[c][3] = fmaf(wv.w, xv, acc[c][3]);
        }
    }
#pragma unroll
    for (int c = 0; c < 8; ++c) {
#pragma unroll
        for (int j = 0; j < 4; ++j) {
            float v = acc[c][j];
#pragma unroll
            for (int s = 32; s > 0; s >>= 1) v += __shfl_xor(v, s, 64);
            acc[c][j] = v;
        }
    }
    if (lane == 0) {
        float* up = upart + ((((size_t)n * TC_NCLS + kc) * 5 + 4) * 128);
#pragma unroll
        for (int c = 0; c < 8; ++c)
            *(float4*)&up[c * 16 + oq * 4] =
                make_float4(acc[c][0], acc[c][1], acc[c][2], acc[c][3]);
    }
}

// ---------------------------------------------------------------------------
// K6b: sum partials (alpha for slots 0-3, beta for slot 4) + routing -> out.
__global__ __launch_bounds__(64) void k_digit_route(
    const float* __restrict__ upart, const float* __restrict__ alphap,
    const float* __restrict__ betap, float* __restrict__ out)
{
    const int kc = blockIdx.x, n = blockIdx.y;
    const int tid = threadIdx.x;
    const float alpha = alphap[0], beta = betap[0];
    __shared__ float ul[8][16];
    __shared__ float sjo[16];
    __shared__ float bc[8];
    __shared__ float fac[1];

    const float* up = upart + (((size_t)n * TC_NCLS + kc) * 5) * 128;
    for (int i = tid; i < 128; i += 64) {
        float sa = up[0 * 128 + i] + up[1 * 128 + i] + up[2 * 128 + i] + up[3 * 128 + i];
        ul[i >> 4][i & 15] = alpha * sa + beta * up[4 * 128 + i];
    }
    __syncthreads();

    if (tid < 16) {
        float sv = 0.f;
#pragma unroll
        for (int c = 0; c < 8; ++c) sv += ul[c][tid];
        sjo[tid] = sv * 0.125f;
    }
    __syncthreads();
    if (tid == 0) {
        float sq = 0.f;
#pragma unroll
        for (int oo = 0; oo < 16; ++oo) sq += sjo[oo] * sjo[oo];
        fac[0] = sq / ((1.f + sq) * (sq + 1e-8f));
    }
    __syncthreads();
    if (tid < 8) {
        float vf = fac[0];
        float sv = 0.f;
#pragma unroll
        for (int oo = 0; oo < 16; ++oo) sv += ul[tid][oo] * (vf * sjo[oo]);
        bc[tid] = sv;
    }
    __syncthreads();
    if (tid < 16) {
        float bmax = -1e30f;
#pragma unroll
        for (int c = 0; c < 8; ++c) bmax = fmaxf(bmax, bc[c]);
        float e[8]; float es = 0.f;
#pragma unroll
        for (int c = 0; c < 8; ++c) { e[c] = __expf(bc[c] - bmax); es += e[c]; }
        float inv = 1.f / es;
        float sv = 0.f;
#pragma unroll
        for (int c = 0; c < 8; ++c) sv += e[c] * inv * ul[c][tid];
        sjo[tid] = sv;
    }
    __syncthreads();
    if (tid == 0) {
        float sq = 0.f;
#pragma unroll
        for (int oo = 0; oo < 16; ++oo) sq += sjo[oo] * sjo[oo];
        fac[0] = sq / ((1.f + sq) * (sq + 1e-8f));
    }
    __syncthreads();
    if (tid < 16) {
        out[((size_t)n * TC_NCLS + kc) * 16 + tid] = fac[0] * sjo[tid];
    }
}

// ---------------------------------------------------------------------------
extern "C" void kernel_launch(void* const* d_in, const int* in_sizes, int n_in,
                              void* d_out, int out_size, void* d_ws, size_t ws_size,
                              hipStream_t stream) {
    const float* X   = (const float*)d_in[0];
    const float* w1  = (const float*)d_in[1];
    const float* w2  = (const float*)d_in[2];
    const float* wA  = (const float*)d_in[3];
    const float* bA  = (const float*)d_in[4];
    const float* wB  = (const float*)d_in[5];
    const float* bB  = (const float*)d_in[6];
    const float* wk  = (const float*)d_in[7];
    const float* bk  = (const float*)d_in[8];
    const float* Wd  = (const float*)d_in[9];
    const float* alphap = (const float*)d_in[10];
    const float* betap  = (const float*)d_in[11];
    float* out = (float*)d_out;

    float* ws  = (float*)d_ws;
    float* x   = ws;                     // [64][64][1024] = 4194304
    float* xs  = ws + 4194304;           // [64][64][1024] = 4194304
    float* xbS = ws + 8388608;           // [64][8][8][128] = 65536
    float* xB  = ws + 8454144;           // [64][8][128] region = 65536
    float* w2r = ws + 8519680;           // 20480 floats (psi_m repacked weights)
    unsigned short* xa_bf = (unsigned short*)(ws + 8540160); // [32][64][8][1024] bf16 = 16.8M ushorts
    // x region dead after cellB_conv -> Cell_A routing writes bf16 a_bf there:
    unsigned short* a_bf = (unsigned short*)x;      // 4194304 ushorts
    // xs region dead after cellA_conv -> digit stage scratch:
    float* upart = xs;                              // 409600 floats
    unsigned short* wt_bf = (unsigned short*)(xs + 2621440); // 1310720 ushorts

    const size_t need = (size_t)(8540160 + 8388608) * sizeof(float);
    const bool split = ws_size >= need;

    k_conv1<<<dim3(64, 64), 256, 0, stream>>>(X, w1, x);
    k_repack_w2<<<dim3(80), 256, 0, stream>>>(w2, w2r);
    k_psim<<<dim3(1024), 256, 0, stream>>>(x, w2r, xs);
    k_squash_rows<<<dim3(4096), 256, 0, stream>>>(xs);
    k_cellB_conv<<<dim3(8, 64), 256, 0, stream>>>(x, wB, bB, wk, bk, xbS);
    k_routeB<<<dim3(8, 64), 128, 0, stream>>>(xbS, xB);
    if (split) {
        for (int g = 0; g < 2; ++g) {
            k_cellA_conv<<<dim3(16, 32), 256, 0, stream>>>(xs, wA, bA, xa_bf, g * 32);
            k_cellA_route<<<dim3(64, 32), 256, 0, stream>>>(xa_bf, a_bf, g * 32);
        }
    } else {
        k_cellA<<<dim3(64, 64), 256, 0, stream>>>(xs, wA, bA, a_bf);
    }
    // digit stage (xs region reused)
    k_cvtW<<<dim3(16, 10), 256, 0, stream>>>(Wd, wt_bf);
    k_digit_mfma<<<dim3(1280), 64, 0, stream>>>(a_bf, wt_bf, upart);
    k_digit_tail<<<dim3(10, 64), 256, 0, stream>>>(xB, Wd, upart);
    k_digit_route<<<dim3(10, 64), 64, 0, stream>>>(upart, alphap, betap, out);
}